// Round 7
// baseline (124.887 us; speedup 1.0000x reference)
//
#include <hip/hip_runtime.h>
#include <hip/hip_bf16.h>

#define NB 4
#define HWN 4096
#define CD 64
#define NSTRIDE (HWN * CD)  // 262144 elems per batch in all swizzled buffers

typedef short short8 __attribute__((ext_vector_type(8), may_alias));
typedef short short4v __attribute__((ext_vector_type(4), may_alias));
typedef float f32x4 __attribute__((ext_vector_type(4), may_alias));
typedef unsigned int uint4v __attribute__((ext_vector_type(4), may_alias));

__device__ constexpr float C1 = 0.18033688011112042f; // log2(e)/8 (folded into Qs)

__device__ __forceinline__ unsigned short f2bf(float f) {
    unsigned u = __builtin_bit_cast(unsigned, f);
    u = (u + 0x7FFFu + ((u >> 16) & 1u)) >> 16;  // RTN-even
    return (unsigned short)u;
}

__device__ __forceinline__ float fexp2(float x) {
#if __has_builtin(__builtin_amdgcn_exp2f)
    return __builtin_amdgcn_exp2f(x);
#else
    return exp2f(x);
#endif
}

// pack two fp32 -> bf16x2 word (RN-even, same rounding as f2bf)
__device__ __forceinline__ unsigned pk2(float a, float b) {
    __hip_bfloat162 h = __float22bfloat162_rn(float2{a, b});
    unsigned u;
    __builtin_memcpy(&u, &h, 4);
    return u;
}

// Frag-major swizzle for a row-major [R][64] matrix, 16-row tiles:
// elem(row, c) -> tile = row>>4, half = c>>5, lane l = ((c>>3)&3)*16 + (row&15),
// offset = tile*1024 + half*512 + l*8 + (c&7).
__device__ __forceinline__ size_t qk_swz(int row, int c) {
    return (size_t)(row >> 4) * 1024 + (c >> 5) * 512 +
           ((((c >> 3) & 3) * 16 + (row & 15)) * 8) + (c & 7);
}

// K row permutation: within each 32-row group, storage tile0 row (g*4+m) holds
// actual k=g*8+m, tile1 row (g*4+m) holds g*8+4+m. QK output registers
// (tile0 regs = elem 0..3, tile1 regs = elem 4..7, at lane quad: k = quad*8+elem)
// then form a legal 16x16x32 B-frag for the PV MFMA, AND give each lane a known
// contiguous k-range (quad*8..quad*8+7) for per-k C-operand init / 1/l fold.
// (Mapping end-to-end verified by round-2..6 correctness passes.)
__device__ __forceinline__ int k_perm_row(int r) {
    int G = r >> 5, a = r & 31;
    int j = a & 7, g = a >> 3;
    return (G << 5) + ((j >> 2) << 4) + g * 4 + (j & 3);
}

// ---------- prep: Qs = bf16(C1*Q) swizzled, Ks = bf16(K) swizzled+permuted,
//            Vts = K32-A-frag-major bf16(V) (l-normalization folded into attn).
// Blocks 0-15 zero the l accumulator. Blocks 256-511 also transpose V.
__global__ __launch_bounds__(256) void cvt_qkv(const float* __restrict__ Q,
                                               const float* __restrict__ K,
                                               const float* __restrict__ V,
                                               unsigned short* __restrict__ Qs,
                                               unsigned short* __restrict__ Ks,
                                               unsigned short* __restrict__ Vts,
                                               float* __restrict__ l) {
    __shared__ float tile[64][65];
    int tid = threadIdx.x;
    if (blockIdx.x < 16) {
        int zi = blockIdx.x * 256 + tid;   // 4096 threads x f32x4 = 16384 floats
        *(f32x4*)(l + (size_t)zi * 4) = f32x4{0.f, 0.f, 0.f, 0.f};
    }
    {
        int i = (blockIdx.x * 256 + tid) * 4;
        int rg = i >> 6, c = i & 63;
        int n = rg >> 12, r = rg & 4095;
        float4 q = *(const float4*)(Q + i);
        float4 k = *(const float4*)(K + i);
        ushort4 qo, ko;
        qo.x = f2bf(q.x * C1); qo.y = f2bf(q.y * C1);
        qo.z = f2bf(q.z * C1); qo.w = f2bf(q.w * C1);
        ko.x = f2bf(k.x); ko.y = f2bf(k.y); ko.z = f2bf(k.z); ko.w = f2bf(k.w);
        *(ushort4*)(Qs + (size_t)n * NSTRIDE + qk_swz(r, c)) = qo;
        *(ushort4*)(Ks + (size_t)n * NSTRIDE + qk_swz(k_perm_row(r), c)) = ko;
    }
    // V transpose part: 256 blocks handle (n, 64-k chunk) each
    if (blockIdx.x >= 256 && blockIdx.x < 512) {
        int bx = blockIdx.x - 256;          // 0..255
        int n = bx >> 6, kbase = (bx & 63) * 64;
#pragma unroll
        for (int i = 0; i < 16; ++i) {
            int e = i * 256 + tid;
            int k = e >> 6, c = e & 63;
            tile[c][k] = V[((size_t)(n * HWN + kbase + k)) * CD + c];
        }
        __syncthreads();
#pragma unroll
        for (int i = 0; i < 2; ++i) {
            int s = i * 256 + tid;        // 0..511
            int kb32 = s >> 8;            // 0..1 local 32k block
            int ct = (s >> 6) & 3;        // c-tile
            int ll = s & 63;              // dest lane
            int cc = ct * 16 + (ll & 15);
            int k0 = kb32 * 32 + ((ll >> 4) & 3) * 8;  // quad*8
            short8 v;
#pragma unroll
            for (int j = 0; j < 8; ++j)
                v[j] = (short)f2bf(tile[cc][k0 + j]);
            size_t off = (size_t)n * NSTRIDE + (size_t)((kbase >> 5) + kb32) * 2048 +
                         ct * 512 + ll * 8;
            *(short8*)(Vts + off) = v;
        }
    }
}

// ---------- phase 1: l[n,k] = sum_q exp2(dot(C1*Q[q], K[k])) ----------
// Wave holds 64 stationary k (4 A-frag pairs); Q stream register-prefetched
// two chunks deep, shared by all 4 stationary tiles.
// TLP round: grid (16 k-blocks, NB, 32 q-slices of 128 q) = 2048 blocks
// (8 blocks/CU, was 4) - every kernel here sat at ~24% occupancy and 2-3x
// above issue floor: latency-bound at low TLP, so double resident waves.
__global__ __attribute__((amdgpu_flat_work_group_size(256, 256), amdgpu_waves_per_eu(2, 8)))
void lsum_kernel(const unsigned short* __restrict__ Qs,
                 const unsigned short* __restrict__ Ks,
                 float* __restrict__ l) {
    int tid = threadIdx.x;
    int w = tid >> 6, lane = tid & 63, quad = lane >> 4, m16 = lane & 15;
    int n = blockIdx.y;
    int kbase = blockIdx.x * 256 + w * 64;

    const unsigned short* Kp = Ks + (size_t)n * NSTRIDE + (kbase >> 4) * 1024 + lane * 8;
    short8 ka0 = *(const short8*)(Kp);
    short8 ka1 = *(const short8*)(Kp + 512);
    short8 kb0 = *(const short8*)(Kp + 1024);
    short8 kb1 = *(const short8*)(Kp + 1536);
    short8 kc0 = *(const short8*)(Kp + 2048);
    short8 kc1 = *(const short8*)(Kp + 2560);
    short8 kd0 = *(const short8*)(Kp + 3072);
    short8 kd1 = *(const short8*)(Kp + 3584);

    // 8 Q-chunks (128 q rows) per z-slice
    const unsigned short* Qp = Qs + (size_t)n * NSTRIDE + blockIdx.z * 8192 + lane * 8;

    short8 qc0 = *(const short8*)(Qp);
    short8 qc1 = *(const short8*)(Qp + 512);
    short8 qn0 = *(const short8*)(Qp + 1024);
    short8 qn1 = *(const short8*)(Qp + 1536);
    Qp += 2048;

    float lA[4] = {0.f, 0.f, 0.f, 0.f};
    float lB[4] = {0.f, 0.f, 0.f, 0.f};
    float lC[4] = {0.f, 0.f, 0.f, 0.f};
    float lD[4] = {0.f, 0.f, 0.f, 0.f};
#pragma unroll 2
    for (int qc = 0; qc < 8; ++qc) {
        // prefetch chunk qc+2 (tail overreads 2 chunks: stays inside ws, safe)
        short8 qm0 = *(const short8*)(Qp);
        short8 qm1 = *(const short8*)(Qp + 512);
        f32x4 a = {0.f, 0.f, 0.f, 0.f}, b = a, c = a, d = a;
        __builtin_amdgcn_s_setprio(1);
        a = __builtin_amdgcn_mfma_f32_16x16x32_bf16(ka0, qc0, a, 0, 0, 0);
        a = __builtin_amdgcn_mfma_f32_16x16x32_bf16(ka1, qc1, a, 0, 0, 0);
        b = __builtin_amdgcn_mfma_f32_16x16x32_bf16(kb0, qc0, b, 0, 0, 0);
        b = __builtin_amdgcn_mfma_f32_16x16x32_bf16(kb1, qc1, b, 0, 0, 0);
        c = __builtin_amdgcn_mfma_f32_16x16x32_bf16(kc0, qc0, c, 0, 0, 0);
        c = __builtin_amdgcn_mfma_f32_16x16x32_bf16(kc1, qc1, c, 0, 0, 0);
        d = __builtin_amdgcn_mfma_f32_16x16x32_bf16(kd0, qc0, d, 0, 0, 0);
        d = __builtin_amdgcn_mfma_f32_16x16x32_bf16(kd1, qc1, d, 0, 0, 0);
        __builtin_amdgcn_s_setprio(0);
#pragma unroll
        for (int r = 0; r < 4; ++r) {
            lA[r] += fexp2(a[r]);
            lB[r] += fexp2(b[r]);
            lC[r] += fexp2(c[r]);
            lD[r] += fexp2(d[r]);
        }
        qc0 = qn0; qc1 = qn1;
        qn0 = qm0; qn1 = qm1;
        Qp += 1024;
    }
#pragma unroll
    for (int r = 0; r < 4; ++r)
        for (int d1 = 1; d1 < 16; d1 <<= 1) {
            lA[r] += __shfl_xor(lA[r], d1);
            lB[r] += __shfl_xor(lB[r], d1);
            lC[r] += __shfl_xor(lC[r], d1);
            lD[r] += __shfl_xor(lD[r], d1);
        }
    if (m16 == 0) {
        // permuted rows: tile a row quad*4+r = k quad*8+r; b = +4; c/d = +32
        float* lp = l + n * HWN + kbase + quad * 8;
#pragma unroll
        for (int r = 0; r < 4; ++r) {
            atomicAdd(lp + r, lA[r]);
            atomicAdd(lp + 4 + r, lB[r]);
            atomicAdd(lp + 32 + r, lC[r]);
            atomicAdd(lp + 36 + r, lD[r]);
        }
    }
}

// ---------- phase 2: out[q,c] = sum_k exp2(s'_kq - log2 l[k]) * V[k][c] ----------
// grid (32 q-blocks of 128, NB, ns k-slices); ns=16 -> 2048 blocks = 8/CU
// (TLP round: occupancy was 24%, latency-bound). Wave w owns TWO 16-q tiles
// (qbase, qbase+64) sharing every K/V load. Permuted-K QK output registers
// concatenate into a legal 16x16x32 B-frag -> PV is 8 MFMAs/iter at K=32.
// 1/l folded into the QK MFMA C-operand (rls = -log2 l). Register K prefetch
// one chunk ahead; V frags hoisted to iter top. NO device-scope fences
// (round-2 lesson). Separate reduce dispatch.
__global__ __attribute__((amdgpu_flat_work_group_size(256, 256), amdgpu_waves_per_eu(2, 8)))
void attn_kernel(const unsigned short* __restrict__ Qs,
                 const unsigned short* __restrict__ Ks,
                 const unsigned short* __restrict__ Vts,
                 const float* __restrict__ l,
                 float* __restrict__ partial,
                 int nit) {
    __shared__ float rls[2048];   // covers kspan down to ns=2
    int tid = threadIdx.x;
    int w = tid >> 6, lane = tid & 63, quad = lane >> 4, m16 = lane & 15;
    int n = blockIdx.y;
    int qbase = blockIdx.x * 128 + w * 16;   // second tile at +64

    // -log2(l) table for this block's k-slice (folded into MFMA C-init)
    int kspan = nit * 32;
    int kk0 = blockIdx.z * kspan;
    for (int i = tid; i < kspan; i += 256)
        rls[i] = -__log2f(l[n * HWN + kk0 + i]);

    const unsigned short* Qp = Qs + (size_t)n * NSTRIDE + (qbase >> 4) * 1024 + lane * 8;
    short8 qa0 = *(const short8*)(Qp);
    short8 qa1 = *(const short8*)(Qp + 512);
    short8 qb0 = *(const short8*)(Qp + 4096);        // +64 q rows = 4 frag tiles
    short8 qb1 = *(const short8*)(Qp + 4096 + 512);

    size_t kofs = (size_t)blockIdx.z * (size_t)nit * 2048;  // 32k-chunk = 2048 elems
    const unsigned short* Kp = Ks + (size_t)n * NSTRIDE + kofs + lane * 8;
    const unsigned short* Vp = Vts + (size_t)n * NSTRIDE + kofs + lane * 8;

    f32x4 oA[4], oB[4];
#pragma unroll
    for (int ct = 0; ct < 4; ++ct) { oA[ct] = f32x4{0.f, 0.f, 0.f, 0.f}; oB[ct] = oA[ct]; }

    // prologue: K frags for chunk 0
    short8 kf00 = *(const short8*)(Kp);
    short8 kf01 = *(const short8*)(Kp + 512);
    short8 kf10 = *(const short8*)(Kp + 1024);
    short8 kf11 = *(const short8*)(Kp + 1536);

    __syncthreads();   // rls ready

#pragma unroll 2
    for (int it = 0; it < nit; ++it) {
        // prefetch next chunk's K frags (tail overreads into adjacent ws: safe)
        short8 kn00 = *(const short8*)(Kp + 2048);
        short8 kn01 = *(const short8*)(Kp + 2560);
        short8 kn10 = *(const short8*)(Kp + 3072);
        short8 kn11 = *(const short8*)(Kp + 3584);
        // hoist current V frags: QK + exp phase covers their latency
        short8 vf0 = *(const short8*)(Vp);
        short8 vf1 = *(const short8*)(Vp + 512);
        short8 vf2 = *(const short8*)(Vp + 1024);
        short8 vf3 = *(const short8*)(Vp + 1536);

        // -log2(l) for this lane's k-range (k = it*32 + quad*8 + elem)
        const float* rlp = rls + it * 32 + quad * 8;
        f32x4 rlo = *(const f32x4*)(rlp);
        f32x4 rhi = *(const f32x4*)(rlp + 4);

        // S' tiles [16k x 16q] + lr[k] via C-operand; both q-tiles share K frags
        f32x4 s00 = rlo, s01 = rhi, s10 = rlo, s11 = rhi;
        __builtin_amdgcn_s_setprio(1);
        s00 = __builtin_amdgcn_mfma_f32_16x16x32_bf16(kf00, qa0, s00, 0, 0, 0);
        s00 = __builtin_amdgcn_mfma_f32_16x16x32_bf16(kf01, qa1, s00, 0, 0, 0);
        s01 = __builtin_amdgcn_mfma_f32_16x16x32_bf16(kf10, qa0, s01, 0, 0, 0);
        s01 = __builtin_amdgcn_mfma_f32_16x16x32_bf16(kf11, qa1, s01, 0, 0, 0);
        s10 = __builtin_amdgcn_mfma_f32_16x16x32_bf16(kf00, qb0, s10, 0, 0, 0);
        s10 = __builtin_amdgcn_mfma_f32_16x16x32_bf16(kf01, qb1, s10, 0, 0, 0);
        s11 = __builtin_amdgcn_mfma_f32_16x16x32_bf16(kf10, qb0, s11, 0, 0, 0);
        s11 = __builtin_amdgcn_mfma_f32_16x16x32_bf16(kf11, qb1, s11, 0, 0, 0);
        __builtin_amdgcn_s_setprio(0);

        // P = exp2(S'+lr) -> full K=32 B-frags in registers (tile0 regs =
        // elem 0..3, tile1 regs = elem 4..7; k = quad*8+elem by permutation)
        uint4v wa = {pk2(fexp2(s00[0]), fexp2(s00[1])), pk2(fexp2(s00[2]), fexp2(s00[3])),
                     pk2(fexp2(s01[0]), fexp2(s01[1])), pk2(fexp2(s01[2]), fexp2(s01[3]))};
        uint4v wb = {pk2(fexp2(s10[0]), fexp2(s10[1])), pk2(fexp2(s10[2]), fexp2(s10[3])),
                     pk2(fexp2(s11[0]), fexp2(s11[1])), pk2(fexp2(s11[2]), fexp2(s11[3]))};
        short8 pA = __builtin_bit_cast(short8, wa);
        short8 pB = __builtin_bit_cast(short8, wb);

        // PV: per c-tile ONE 16x16x32 MFMA per q-tile (V frag = full K=32 A-frag)
        __builtin_amdgcn_s_setprio(1);
        oA[0] = __builtin_amdgcn_mfma_f32_16x16x32_bf16(vf0, pA, oA[0], 0, 0, 0);
        oB[0] = __builtin_amdgcn_mfma_f32_16x16x32_bf16(vf0, pB, oB[0], 0, 0, 0);
        oA[1] = __builtin_amdgcn_mfma_f32_16x16x32_bf16(vf1, pA, oA[1], 0, 0, 0);
        oB[1] = __builtin_amdgcn_mfma_f32_16x16x32_bf16(vf1, pB, oB[1], 0, 0, 0);
        oA[2] = __builtin_amdgcn_mfma_f32_16x16x32_bf16(vf2, pA, oA[2], 0, 0, 0);
        oB[2] = __builtin_amdgcn_mfma_f32_16x16x32_bf16(vf2, pB, oB[2], 0, 0, 0);
        oA[3] = __builtin_amdgcn_mfma_f32_16x16x32_bf16(vf3, pA, oA[3], 0, 0, 0);
        oB[3] = __builtin_amdgcn_mfma_f32_16x16x32_bf16(vf3, pB, oB[3], 0, 0, 0);
        __builtin_amdgcn_s_setprio(0);

        kf00 = kn00; kf01 = kn01; kf10 = kn10; kf11 = kn11;
        Kp += 2048;
        Vp += 2048;
    }

    // o{A,B}[ct][r] = outT[c = ct*16 + quad*4 + r][q] -> contiguous f32x4 stores
    float* ppA = partial + (size_t)blockIdx.z * (NB * HWN * CD) +
                 ((size_t)(n * HWN + qbase + m16)) * CD + quad * 4;
    float* ppB = ppA + (size_t)64 * CD;
#pragma unroll
    for (int ct = 0; ct < 4; ++ct) {
        *(f32x4*)(ppA + ct * 16) = oA[ct];
        *(f32x4*)(ppB + ct * 16) = oB[ct];
    }
}

// ---------- final: out = sum of ns partial slices ----------
__global__ __launch_bounds__(256) void reduce_out(const float* __restrict__ p,
                                                  float* __restrict__ out, int ns) {
    int i = (blockIdx.x * 256 + threadIdx.x) * 4;
    f32x4 a = *(const f32x4*)(p + i);
    for (int s = 1; s < ns; ++s)
        a = a + *(const f32x4*)(p + (size_t)s * (NB * HWN * CD) + i);
    *(f32x4*)(out + i) = a;
}

extern "C" void kernel_launch(void* const* d_in, const int* in_sizes, int n_in,
                              void* d_out, int out_size, void* d_ws, size_t ws_size,
                              hipStream_t stream) {
    const float* Q = (const float*)d_in[0];
    const float* K = (const float*)d_in[1];
    const float* V = (const float*)d_in[2];
    float* out = (float*)d_out;

    char* ws = (char*)d_ws;
    unsigned short* Qs  = (unsigned short*)(ws);                   // 2 MB
    unsigned short* Ks  = (unsigned short*)(ws + (1u << 21));      // 2 MB
    unsigned short* Vts = (unsigned short*)(ws + (2u << 21));      // 2 MB
    float* l       = (float*)(ws + (3u << 21));                    // 64 KB
    float* partial = (float*)(ws + (4u << 21));                    // ns * 4 MB

    size_t base = (size_t)(4u << 21);
    size_t slice = (size_t)NB * HWN * CD * sizeof(float);
    int ns = (ws_size >= base + 16 * slice) ? 16
           : (ws_size >= base + 8 * slice) ? 8
           : (ws_size >= base + 4 * slice) ? 4 : 2;
    int nit = HWN / ns / 32;  // ns=16 -> 8 iters of 32k

    cvt_qkv<<<1024, 256, 0, stream>>>(Q, K, V, Qs, Ks, Vts, l);
    lsum_kernel<<<dim3(16, NB, 32), 256, 0, stream>>>(Qs, Ks, l);
    attn_kernel<<<dim3(32, NB, ns), 256, 0, stream>>>(Qs, Ks, Vts, l, partial, nit);
    reduce_out<<<1024, 256, 0, stream>>>(partial, out, ns);
}

// Round 8
// 110.088 us; speedup vs baseline: 1.1344x; 1.1344x over previous
//
#include <hip/hip_runtime.h>
#include <hip/hip_bf16.h>

#define NB 4
#define HWN 4096
#define CD 64
#define NSTRIDE (HWN * CD)  // 262144 elems per batch in all swizzled buffers

typedef short short8 __attribute__((ext_vector_type(8), may_alias));
typedef short short4v __attribute__((ext_vector_type(4), may_alias));
typedef float f32x4 __attribute__((ext_vector_type(4), may_alias));
typedef unsigned int uint4v __attribute__((ext_vector_type(4), may_alias));

__device__ constexpr float C1 = 0.18033688011112042f; // log2(e)/8 (folded into Qs)

__device__ __forceinline__ unsigned short f2bf(float f) {
    unsigned u = __builtin_bit_cast(unsigned, f);
    u = (u + 0x7FFFu + ((u >> 16) & 1u)) >> 16;  // RTN-even
    return (unsigned short)u;
}

__device__ __forceinline__ float fexp2(float x) {
#if __has_builtin(__builtin_amdgcn_exp2f)
    return __builtin_amdgcn_exp2f(x);
#else
    return exp2f(x);
#endif
}

// pack two fp32 -> bf16x2 word (RN-even, same rounding as f2bf)
__device__ __forceinline__ unsigned pk2(float a, float b) {
    __hip_bfloat162 h = __float22bfloat162_rn(float2{a, b});
    unsigned u;
    __builtin_memcpy(&u, &h, 4);
    return u;
}

// Frag-major swizzle for a row-major [R][64] matrix, 16-row tiles:
// elem(row, c) -> tile = row>>4, half = c>>5, lane l = ((c>>3)&3)*16 + (row&15),
// offset = tile*1024 + half*512 + l*8 + (c&7).
__device__ __forceinline__ size_t qk_swz(int row, int c) {
    return (size_t)(row >> 4) * 1024 + (c >> 5) * 512 +
           ((((c >> 3) & 3) * 16 + (row & 15)) * 8) + (c & 7);
}

// K row permutation: within each 32-row group, storage tile0 row (g*4+m) holds
// actual k=g*8+m, tile1 row (g*4+m) holds g*8+4+m. QK output registers
// (tile0 regs = elem 0..3, tile1 regs = elem 4..7, at lane quad: k = quad*8+elem)
// then form a legal 16x16x32 B-frag for the PV MFMA, AND give each lane a known
// contiguous k-range (quad*8..quad*8+7) for per-k C-operand init / 1/l fold.
// (Mapping end-to-end verified by round-2..7 correctness passes.)
__device__ __forceinline__ int k_perm_row(int r) {
    int G = r >> 5, a = r & 31;
    int j = a & 7, g = a >> 3;
    return (G << 5) + ((j >> 2) << 4) + g * 4 + (j & 3);
}

// ---------- prep: Qs = bf16(C1*Q) swizzled, Ks = bf16(K) swizzled+permuted,
//            Vts = K32-A-frag-major bf16(V) (l-normalization folded into attn).
// Blocks 0-15 zero the l accumulator. Blocks 256-511 also transpose V.
__global__ __launch_bounds__(256) void cvt_qkv(const float* __restrict__ Q,
                                               const float* __restrict__ K,
                                               const float* __restrict__ V,
                                               unsigned short* __restrict__ Qs,
                                               unsigned short* __restrict__ Ks,
                                               unsigned short* __restrict__ Vts,
                                               float* __restrict__ l) {
    __shared__ float tile[64][65];
    int tid = threadIdx.x;
    if (blockIdx.x < 16) {
        int zi = blockIdx.x * 256 + tid;   // 4096 threads x f32x4 = 16384 floats
        *(f32x4*)(l + (size_t)zi * 4) = f32x4{0.f, 0.f, 0.f, 0.f};
    }
    {
        int i = (blockIdx.x * 256 + tid) * 4;
        int rg = i >> 6, c = i & 63;
        int n = rg >> 12, r = rg & 4095;
        float4 q = *(const float4*)(Q + i);
        float4 k = *(const float4*)(K + i);
        ushort4 qo, ko;
        qo.x = f2bf(q.x * C1); qo.y = f2bf(q.y * C1);
        qo.z = f2bf(q.z * C1); qo.w = f2bf(q.w * C1);
        ko.x = f2bf(k.x); ko.y = f2bf(k.y); ko.z = f2bf(k.z); ko.w = f2bf(k.w);
        *(ushort4*)(Qs + (size_t)n * NSTRIDE + qk_swz(r, c)) = qo;
        *(ushort4*)(Ks + (size_t)n * NSTRIDE + qk_swz(k_perm_row(r), c)) = ko;
    }
    // V transpose part: 256 blocks handle (n, 64-k chunk) each
    if (blockIdx.x >= 256 && blockIdx.x < 512) {
        int bx = blockIdx.x - 256;          // 0..255
        int n = bx >> 6, kbase = (bx & 63) * 64;
#pragma unroll
        for (int i = 0; i < 16; ++i) {
            int e = i * 256 + tid;
            int k = e >> 6, c = e & 63;
            tile[c][k] = V[((size_t)(n * HWN + kbase + k)) * CD + c];
        }
        __syncthreads();
#pragma unroll
        for (int i = 0; i < 2; ++i) {
            int s = i * 256 + tid;        // 0..511
            int kb32 = s >> 8;            // 0..1 local 32k block
            int ct = (s >> 6) & 3;        // c-tile
            int ll = s & 63;              // dest lane
            int cc = ct * 16 + (ll & 15);
            int k0 = kb32 * 32 + ((ll >> 4) & 3) * 8;  // quad*8
            short8 v;
#pragma unroll
            for (int j = 0; j < 8; ++j)
                v[j] = (short)f2bf(tile[cc][k0 + j]);
            size_t off = (size_t)n * NSTRIDE + (size_t)((kbase >> 5) + kb32) * 2048 +
                         ct * 512 + ll * 8;
            *(short8*)(Vts + off) = v;
        }
    }
}

// ---------- phase 1: l[n,k] = sum_q exp2(dot(C1*Q[q], K[k])) ----------
// Wave holds 64 stationary k (4 A-frag pairs); Q stream register-prefetched
// two chunks deep (~440 cyc of L2-latency cover), shared by all 4 stationary
// tiles. grid (16 k-blocks of 256, NB, 16 q-slices).
// With the K row permutation: tile a row (quad*4+r) = actual k quad*8+r,
// tile b = +4, tiles c/d = +32 (second 32-group).
__global__ __attribute__((amdgpu_flat_work_group_size(256, 256), amdgpu_waves_per_eu(2, 4)))
void lsum_kernel(const unsigned short* __restrict__ Qs,
                 const unsigned short* __restrict__ Ks,
                 float* __restrict__ l) {
    int tid = threadIdx.x;
    int w = tid >> 6, lane = tid & 63, quad = lane >> 4, m16 = lane & 15;
    int n = blockIdx.y;
    int kbase = blockIdx.x * 256 + w * 64;

    const unsigned short* Kp = Ks + (size_t)n * NSTRIDE + (kbase >> 4) * 1024 + lane * 8;
    short8 ka0 = *(const short8*)(Kp);
    short8 ka1 = *(const short8*)(Kp + 512);
    short8 kb0 = *(const short8*)(Kp + 1024);
    short8 kb1 = *(const short8*)(Kp + 1536);
    short8 kc0 = *(const short8*)(Kp + 2048);
    short8 kc1 = *(const short8*)(Kp + 2560);
    short8 kd0 = *(const short8*)(Kp + 3072);
    short8 kd1 = *(const short8*)(Kp + 3584);

    const unsigned short* Qp = Qs + (size_t)n * NSTRIDE + blockIdx.z * 16384 + lane * 8;

    short8 qc0 = *(const short8*)(Qp);
    short8 qc1 = *(const short8*)(Qp + 512);
    short8 qn0 = *(const short8*)(Qp + 1024);
    short8 qn1 = *(const short8*)(Qp + 1536);
    Qp += 2048;

    float lA[4] = {0.f, 0.f, 0.f, 0.f};
    float lB[4] = {0.f, 0.f, 0.f, 0.f};
    float lC[4] = {0.f, 0.f, 0.f, 0.f};
    float lD[4] = {0.f, 0.f, 0.f, 0.f};
#pragma unroll 2
    for (int qc = 0; qc < 16; ++qc) {
        // prefetch chunk qc+2 (tail overreads 2 chunks: lands in Qs/Ks ws, safe)
        short8 qm0 = *(const short8*)(Qp);
        short8 qm1 = *(const short8*)(Qp + 512);
        f32x4 a = {0.f, 0.f, 0.f, 0.f}, b = a, c = a, d = a;
        __builtin_amdgcn_s_setprio(1);
        a = __builtin_amdgcn_mfma_f32_16x16x32_bf16(ka0, qc0, a, 0, 0, 0);
        a = __builtin_amdgcn_mfma_f32_16x16x32_bf16(ka1, qc1, a, 0, 0, 0);
        b = __builtin_amdgcn_mfma_f32_16x16x32_bf16(kb0, qc0, b, 0, 0, 0);
        b = __builtin_amdgcn_mfma_f32_16x16x32_bf16(kb1, qc1, b, 0, 0, 0);
        c = __builtin_amdgcn_mfma_f32_16x16x32_bf16(kc0, qc0, c, 0, 0, 0);
        c = __builtin_amdgcn_mfma_f32_16x16x32_bf16(kc1, qc1, c, 0, 0, 0);
        d = __builtin_amdgcn_mfma_f32_16x16x32_bf16(kd0, qc0, d, 0, 0, 0);
        d = __builtin_amdgcn_mfma_f32_16x16x32_bf16(kd1, qc1, d, 0, 0, 0);
        __builtin_amdgcn_s_setprio(0);
#pragma unroll
        for (int r = 0; r < 4; ++r) {
            lA[r] += fexp2(a[r]);
            lB[r] += fexp2(b[r]);
            lC[r] += fexp2(c[r]);
            lD[r] += fexp2(d[r]);
        }
        qc0 = qn0; qc1 = qn1;
        qn0 = qm0; qn1 = qm1;
        Qp += 1024;
    }
#pragma unroll
    for (int r = 0; r < 4; ++r)
        for (int d1 = 1; d1 < 16; d1 <<= 1) {
            lA[r] += __shfl_xor(lA[r], d1);
            lB[r] += __shfl_xor(lB[r], d1);
            lC[r] += __shfl_xor(lC[r], d1);
            lD[r] += __shfl_xor(lD[r], d1);
        }
    if (m16 == 0) {
        // permuted rows: tile a row quad*4+r = k quad*8+r; b = +4; c/d = +32
        float* lp = l + n * HWN + kbase + quad * 8;
#pragma unroll
        for (int r = 0; r < 4; ++r) {
            atomicAdd(lp + r, lA[r]);
            atomicAdd(lp + 4 + r, lB[r]);
            atomicAdd(lp + 32 + r, lC[r]);
            atomicAdd(lp + 36 + r, lD[r]);
        }
    }
}

// ---------- phase 2: out[q,c] = sum_k exp2(s'_kq - log2 l[k]) * V[k][c] ----------
// grid (32 q-blocks of 128, NB, ns k-slices). Wave w owns TWO 16-q tiles
// (qbase, qbase+64) sharing every K/V load. Permuted-K QK output registers
// concatenate into a legal 16x16x32 B-frag -> PV is 8 MFMAs/iter at K=32.
// 1/l FOLDED INTO THE QK MFMA C-OPERAND: rls holds -log2(l); s-tiles init
// with the per-k log values (C/D row k = quad*8+elem matches rls indexing),
// so P = exp2(S'+lr) directly. Register K prefetch one chunk ahead; V frags
// hoisted to iter top; barrier-free main loop. NO device-scope fences
// (round-2 lesson). Separate reduce dispatch.
__global__ __attribute__((amdgpu_flat_work_group_size(256, 256), amdgpu_waves_per_eu(2, 4)))
void attn_kernel(const unsigned short* __restrict__ Qs,
                 const unsigned short* __restrict__ Ks,
                 const unsigned short* __restrict__ Vts,
                 const float* __restrict__ l,
                 float* __restrict__ partial,
                 int nit) {
    __shared__ float rls[2048];   // covers kspan up to ns=2
    int tid = threadIdx.x;
    int w = tid >> 6, lane = tid & 63, quad = lane >> 4, m16 = lane & 15;
    int n = blockIdx.y;
    int qbase = blockIdx.x * 128 + w * 16;   // second tile at +64

    // -log2(l) table for this block's k-slice (folded into MFMA C-init)
    int kspan = nit * 32;
    int kk0 = blockIdx.z * kspan;
    for (int i = tid; i < kspan; i += 256)
        rls[i] = -__log2f(l[n * HWN + kk0 + i]);

    const unsigned short* Qp = Qs + (size_t)n * NSTRIDE + (qbase >> 4) * 1024 + lane * 8;
    short8 qa0 = *(const short8*)(Qp);
    short8 qa1 = *(const short8*)(Qp + 512);
    short8 qb0 = *(const short8*)(Qp + 4096);        // +64 q rows = 4 frag tiles
    short8 qb1 = *(const short8*)(Qp + 4096 + 512);

    size_t kofs = (size_t)blockIdx.z * (size_t)nit * 2048;  // 32k-chunk = 2048 elems
    const unsigned short* Kp = Ks + (size_t)n * NSTRIDE + kofs + lane * 8;
    const unsigned short* Vp = Vts + (size_t)n * NSTRIDE + kofs + lane * 8;

    f32x4 oA[4], oB[4];
#pragma unroll
    for (int ct = 0; ct < 4; ++ct) { oA[ct] = f32x4{0.f, 0.f, 0.f, 0.f}; oB[ct] = oA[ct]; }

    // prologue: K frags for chunk 0
    short8 kf00 = *(const short8*)(Kp);
    short8 kf01 = *(const short8*)(Kp + 512);
    short8 kf10 = *(const short8*)(Kp + 1024);
    short8 kf11 = *(const short8*)(Kp + 1536);

    __syncthreads();   // rls ready

#pragma unroll 2
    for (int it = 0; it < nit; ++it) {
        // prefetch next chunk's K frags (tail overreads into adjacent ws: safe)
        short8 kn00 = *(const short8*)(Kp + 2048);
        short8 kn01 = *(const short8*)(Kp + 2560);
        short8 kn10 = *(const short8*)(Kp + 3072);
        short8 kn11 = *(const short8*)(Kp + 3584);
        // hoist current V frags: QK + exp phase covers their latency
        short8 vf0 = *(const short8*)(Vp);
        short8 vf1 = *(const short8*)(Vp + 512);
        short8 vf2 = *(const short8*)(Vp + 1024);
        short8 vf3 = *(const short8*)(Vp + 1536);

        // -log2(l) for this lane's k-range (k = it*32 + quad*8 + elem)
        const float* rlp = rls + it * 32 + quad * 8;
        f32x4 rlo = *(const f32x4*)(rlp);
        f32x4 rhi = *(const f32x4*)(rlp + 4);

        // S' tiles [16k x 16q] + lr[k] via C-operand; both q-tiles share K frags
        f32x4 s00 = rlo, s01 = rhi, s10 = rlo, s11 = rhi;
        __builtin_amdgcn_s_setprio(1);
        s00 = __builtin_amdgcn_mfma_f32_16x16x32_bf16(kf00, qa0, s00, 0, 0, 0);
        s00 = __builtin_amdgcn_mfma_f32_16x16x32_bf16(kf01, qa1, s00, 0, 0, 0);
        s01 = __builtin_amdgcn_mfma_f32_16x16x32_bf16(kf10, qa0, s01, 0, 0, 0);
        s01 = __builtin_amdgcn_mfma_f32_16x16x32_bf16(kf11, qa1, s01, 0, 0, 0);
        s10 = __builtin_amdgcn_mfma_f32_16x16x32_bf16(kf00, qb0, s10, 0, 0, 0);
        s10 = __builtin_amdgcn_mfma_f32_16x16x32_bf16(kf01, qb1, s10, 0, 0, 0);
        s11 = __builtin_amdgcn_mfma_f32_16x16x32_bf16(kf10, qb0, s11, 0, 0, 0);
        s11 = __builtin_amdgcn_mfma_f32_16x16x32_bf16(kf11, qb1, s11, 0, 0, 0);
        __builtin_amdgcn_s_setprio(0);

        // P = exp2(S'+lr) -> full K=32 B-frags in registers (tile0 regs =
        // elem 0..3, tile1 regs = elem 4..7; k = quad*8+elem by permutation)
        uint4v wa = {pk2(fexp2(s00[0]), fexp2(s00[1])), pk2(fexp2(s00[2]), fexp2(s00[3])),
                     pk2(fexp2(s01[0]), fexp2(s01[1])), pk2(fexp2(s01[2]), fexp2(s01[3]))};
        uint4v wb = {pk2(fexp2(s10[0]), fexp2(s10[1])), pk2(fexp2(s10[2]), fexp2(s10[3])),
                     pk2(fexp2(s11[0]), fexp2(s11[1])), pk2(fexp2(s11[2]), fexp2(s11[3]))};
        short8 pA = __builtin_bit_cast(short8, wa);
        short8 pB = __builtin_bit_cast(short8, wb);

        // PV: per c-tile ONE 16x16x32 MFMA per q-tile (V frag = full K=32 A-frag)
        __builtin_amdgcn_s_setprio(1);
        oA[0] = __builtin_amdgcn_mfma_f32_16x16x32_bf16(vf0, pA, oA[0], 0, 0, 0);
        oB[0] = __builtin_amdgcn_mfma_f32_16x16x32_bf16(vf0, pB, oB[0], 0, 0, 0);
        oA[1] = __builtin_amdgcn_mfma_f32_16x16x32_bf16(vf1, pA, oA[1], 0, 0, 0);
        oB[1] = __builtin_amdgcn_mfma_f32_16x16x32_bf16(vf1, pB, oB[1], 0, 0, 0);
        oA[2] = __builtin_amdgcn_mfma_f32_16x16x32_bf16(vf2, pA, oA[2], 0, 0, 0);
        oB[2] = __builtin_amdgcn_mfma_f32_16x16x32_bf16(vf2, pB, oB[2], 0, 0, 0);
        oA[3] = __builtin_amdgcn_mfma_f32_16x16x32_bf16(vf3, pA, oA[3], 0, 0, 0);
        oB[3] = __builtin_amdgcn_mfma_f32_16x16x32_bf16(vf3, pB, oB[3], 0, 0, 0);
        __builtin_amdgcn_s_setprio(0);

        kf00 = kn00; kf01 = kn01; kf10 = kn10; kf11 = kn11;
        Kp += 2048;
        Vp += 2048;
    }

    // o{A,B}[ct][r] = outT[c = ct*16 + quad*4 + r][q] -> contiguous f32x4 stores
    float* ppA = partial + (size_t)blockIdx.z * (NB * HWN * CD) +
                 ((size_t)(n * HWN + qbase + m16)) * CD + quad * 4;
    float* ppB = ppA + (size_t)64 * CD;
#pragma unroll
    for (int ct = 0; ct < 4; ++ct) {
        *(f32x4*)(ppA + ct * 16) = oA[ct];
        *(f32x4*)(ppB + ct * 16) = oB[ct];
    }
}

// ---------- final: out = sum of ns partial slices ----------
__global__ __launch_bounds__(256) void reduce_out(const float* __restrict__ p,
                                                  float* __restrict__ out, int ns) {
    int i = (blockIdx.x * 256 + threadIdx.x) * 4;
    f32x4 a = *(const f32x4*)(p + i);
    for (int s = 1; s < ns; ++s)
        a = a + *(const f32x4*)(p + (size_t)s * (NB * HWN * CD) + i);
    *(f32x4*)(out + i) = a;
}

extern "C" void kernel_launch(void* const* d_in, const int* in_sizes, int n_in,
                              void* d_out, int out_size, void* d_ws, size_t ws_size,
                              hipStream_t stream) {
    const float* Q = (const float*)d_in[0];
    const float* K = (const float*)d_in[1];
    const float* V = (const float*)d_in[2];
    float* out = (float*)d_out;

    char* ws = (char*)d_ws;
    unsigned short* Qs  = (unsigned short*)(ws);                   // 2 MB
    unsigned short* Ks  = (unsigned short*)(ws + (1u << 21));      // 2 MB
    unsigned short* Vts = (unsigned short*)(ws + (2u << 21));      // 2 MB
    float* l       = (float*)(ws + (3u << 21));                    // 64 KB
    float* partial = (float*)(ws + (4u << 21));                    // ns * 4 MB

    size_t base = (size_t)(4u << 21);
    size_t slice = (size_t)NB * HWN * CD * sizeof(float);
    int ns = (ws_size >= base + 8 * slice) ? 8
           : (ws_size >= base + 4 * slice) ? 4 : 2;
    int nit = HWN / ns / 32;  // ns=8 -> 16 iters of 32k

    cvt_qkv<<<1024, 256, 0, stream>>>(Q, K, V, Qs, Ks, Vts, l);
    lsum_kernel<<<dim3(16, NB, 16), 256, 0, stream>>>(Qs, Ks, l);
    attn_kernel<<<dim3(32, NB, ns), 256, 0, stream>>>(Qs, Ks, Vts, l, partial, nit);
    reduce_out<<<1024, 256, 0, stream>>>(partial, out, ns);
}